// Round 1
// baseline (1027.111 us; speedup 1.0000x reference)
//
#include <hip/hip_runtime.h>
#include <hip/hip_bf16.h>

#define SEQ 512
#define HID 768
#define HEADS 12
#define DH 64
#define LAYERS 12
#define BATCH 32
#define TOK (BATCH*SEQ)   // 16384
#define NPH (BATCH*DH)    // 2048: per-head N dimension of the mix GEMM

typedef __attribute__((ext_vector_type(8))) __bf16 bf16x8;
typedef __attribute__((ext_vector_type(4))) __bf16 bf16x4;
typedef __attribute__((ext_vector_type(4))) float f32x4;

typedef __attribute__((address_space(1))) const void gvoid;
typedef __attribute__((address_space(3))) void svoid;
// async global->LDS, 16B/lane; LDS dest must be wave-uniform base + lane*16 [m97/m104]
__device__ __forceinline__ void async_cp16(const void* g, void* l) {
  __builtin_amdgcn_global_load_lds((gvoid*)g, (svoid*)l, 16, 0, 0);
}

// ---------------- fp32 -> bf16 bulk convert (W, last_w) ----------------
__global__ __launch_bounds__(256) void convert_k(
    const float* __restrict__ src, __bf16* __restrict__ dst) {
  int i = (blockIdx.x * 256 + threadIdx.x) * 4;
  f32x4 v = *(const f32x4*)&src[i];
  bf16x4 b;
#pragma unroll
  for (int j = 0; j < 4; j++) b[j] = (__bf16)v[j];
  *(bf16x4*)&dst[i] = b;
}

// ---------------- embed + layernorm: fp32 in -> bf16 h[tok][c] ----------------
__global__ __launch_bounds__(256) void embed_ln_k(
    const int* __restrict__ x, const float* __restrict__ we,
    const float* __restrict__ pe, const float* __restrict__ te,
    const float* __restrict__ g, const float* __restrict__ be,
    __bf16* __restrict__ h) {
  const int tok = blockIdx.x;
  const int s = tok & (SEQ - 1);
  const int wid = x[tok];
  const int tid = threadIdx.x;
  float v[3];
  float sum = 0.f, sq = 0.f;
#pragma unroll
  for (int j = 0; j < 3; j++) {
    int c = tid + j * 256;
    float val = we[(size_t)wid * HID + c] + pe[(size_t)s * HID + c] + te[c];
    v[j] = val; sum += val; sq += val * val;
  }
#pragma unroll
  for (int off = 32; off > 0; off >>= 1) {
    sum += __shfl_down(sum, off);
    sq  += __shfl_down(sq, off);
  }
  __shared__ float rs_[4], rq_[4];
  const int wv = tid >> 6;
  if ((tid & 63) == 0) { rs_[wv] = sum; rq_[wv] = sq; }
  __syncthreads();
  sum = rs_[0] + rs_[1] + rs_[2] + rs_[3];
  sq  = rq_[0] + rq_[1] + rq_[2] + rq_[3];
  const float mu  = sum * (1.f / HID);
  const float var = sq * (1.f / HID) - mu * mu;
  const float inv = rsqrtf(var + 1e-12f);
#pragma unroll
  for (int j = 0; j < 3; j++) {
    int c = tid + j * 256;
    float o = (v[j] - mu) * inv * g[c] + be[c];
    h[(size_t)tok * HID + c] = (__bf16)o;
  }
}

// ---------------- all-layer M transpose+convert: Mt[l][h][t][s] = bf16(M[l][h][s][t]) ----------------
__global__ __launch_bounds__(256) void transpose_all_m_k(
    const float* __restrict__ M, __bf16* __restrict__ Mt) {
  __shared__ float tile[64][68];            // +4 pad
  const int lh = blockIdx.z;                // layer*HEADS + head
  const int t0 = blockIdx.x * 64, s0 = blockIdx.y * 64;
  const float* src = M + (size_t)lh * SEQ * SEQ;
  __bf16* dst = Mt + (size_t)lh * SEQ * SEQ;
  const int tid = threadIdx.x;
#pragma unroll
  for (int it = 0; it < 4; it++) {
    int e = (it * 256 + tid) * 4;
    int r = e >> 6, c = e & 63;             // tile[r=s][c=t]
    *(f32x4*)&tile[r][c] = *(const f32x4*)&src[(size_t)(s0 + r) * SEQ + t0 + c];
  }
  __syncthreads();
#pragma unroll
  for (int it = 0; it < 2; it++) {
    int e = (it * 256 + tid) * 8;
    int r = e >> 6, c = e & 63;
    bf16x8 vv;
#pragma unroll
    for (int j = 0; j < 8; j++) vv[j] = (__bf16)tile[c + j][r];
    *(bf16x8*)&dst[(size_t)(t0 + r) * SEQ + s0 + c] = vv;
  }
}

// ---------------- flipped dense: X[h][b*64+d][s] = sum_k Wb[h*64+d][k]*h[(b*512+s)][k] ----------------
// Output layout change vs prior round: per head h, X_h is a contiguous [NPH=2048][SEQ=512]
// row-major bf16 matrix with rows nn = b*64+d, cols s — exactly the B-operand layout the
// restructured mix GEMM needs.  Write coalescing identical to before (16 lanes -> 16
// consecutive s, 32-B chunks).
__global__ __launch_bounds__(256) void dense_t_k(
    const __bf16* __restrict__ Wb, const __bf16* __restrict__ hin,
    __bf16* __restrict__ X) {
  __shared__ __bf16 Al[128 * 32];           // unpadded, 64 B rows (global_load_lds layout)
  __shared__ __bf16 Bl[128 * 32];
  const int n0 = blockIdx.x * 128;          // token base
  const int m0 = blockIdx.y * 128;          // dout base
  const int tid = threadIdx.x;
  const int wave = tid >> 6, lane = tid & 63;
  const int wm = (wave >> 1) << 6, wn = (wave & 1) << 6;
  const int lm = lane & 15, q = lane >> 4;
  const int lrow = lane >> 2, lcol = (lane & 3) * 8;  // staging: 4 lanes/row
  f32x4 acc[4][4];
#pragma unroll
  for (int i = 0; i < 4; i++)
#pragma unroll
    for (int j = 0; j < 4; j++) acc[i][j] = {0.f, 0.f, 0.f, 0.f};

  for (int k0 = 0; k0 < HID; k0 += 32) {
    // 8192 B per matrix = 8 chunks x 1024 B; wave w -> chunks {2w,2w+1} of each
#pragma unroll
    for (int it = 0; it < 2; it++) {
      int c = wave * 2 + it;                // chunk: rows [16c,16c+16)
      int row = c * 16 + lrow;
      async_cp16(&Wb[(size_t)(m0 + row) * HID + k0 + lcol], &Al[c * 512 + lane * 8]);
      async_cp16(&hin[(size_t)(n0 + row) * HID + k0 + lcol], &Bl[c * 512 + lane * 8]);
    }
    __syncthreads();
    bf16x8 af[4], bfr[4];
#pragma unroll
    for (int i = 0; i < 4; i++) {
      af[i]  = *(const bf16x8*)&Al[(wm + i * 16 + lm) * 32 + q * 8];
      bfr[i] = *(const bf16x8*)&Bl[(wn + i * 16 + lm) * 32 + q * 8];
    }
#pragma unroll
    for (int mi = 0; mi < 4; mi++)
#pragma unroll
      for (int ni = 0; ni < 4; ni++)
        acc[mi][ni] = __builtin_amdgcn_mfma_f32_16x16x32_bf16(af[mi], bfr[ni], acc[mi][ni], 0, 0, 0);
    __syncthreads();
  }
  // D layout: row(m)=q*4+r, col(n)=lm  [m89/m91]
  // X offset for (dout, tok): h=dout>>6, d=dout&63, b=tok>>9, s=tok&511
  //   -> h*(NPH*SEQ) + (b*64+d)*SEQ + s
#pragma unroll
  for (int mi = 0; mi < 4; mi++)
#pragma unroll
    for (int ni = 0; ni < 4; ni++)
#pragma unroll
      for (int r = 0; r < 4; r++) {
        int dout = m0 + wm + mi * 16 + q * 4 + r;
        int tok  = n0 + wn + ni * 16 + lm;
        int hh = dout >> 6, dd = dout & 63;
        int bb = tok >> 9, ss = tok & (SEQ - 1);
        X[(size_t)hh * (NPH * SEQ) + (size_t)bb * (DH * SEQ) + (size_t)dd * SEQ + ss] =
            (__bf16)acc[mi][ni][r];
      }
}

// ---------------- mixing + bias + relu, restructured as per-head GEMM ----------------
// Per head h: C[t][nn] = sum_s Mt[h][t][s] * X[h][nn][s],  nn = b*64+d  (M=512,N=2048,K=512)
// hout[b][t][h*64+d] = relu(C + bias[h*64+d]).
// Identical proven 128x128/BK=32 block structure as dense_t_k; Mt tiles now re-read
// 16x/layer (vs 32x before), staged bytes per 64 MFMA drop 20KB -> 16KB.
__global__ __launch_bounds__(256) void mix_relu_k(
    const __bf16* __restrict__ Mtl, const __bf16* __restrict__ X,
    const float* __restrict__ bias_l, __bf16* __restrict__ hout) {
  __shared__ __bf16 Al[128 * 32];           // Mt rows (m = t), unpadded 64 B rows
  __shared__ __bf16 Bl[128 * 32];           // X rows (n = b*64+d)
  const int t0 = blockIdx.x * 128;          // t base (M)
  const int n0 = blockIdx.y * 128;          // nn base (N)
  const int head = blockIdx.z;
  const __bf16* A = Mtl + (size_t)head * SEQ * SEQ;      // [512][512], rows t, k=s contiguous
  const __bf16* B = X + (size_t)head * (NPH * SEQ);      // [2048][512], rows nn, k=s contiguous
  const int tid = threadIdx.x;
  const int wave = tid >> 6, lane = tid & 63;
  const int wm = (wave >> 1) << 6, wn = (wave & 1) << 6;
  const int lm = lane & 15, q = lane >> 4;
  const int lrow = lane >> 2, lcol = (lane & 3) * 8;
  f32x4 acc[4][4];
#pragma unroll
  for (int i = 0; i < 4; i++)
#pragma unroll
    for (int j = 0; j < 4; j++) acc[i][j] = {0.f, 0.f, 0.f, 0.f};

  for (int k0 = 0; k0 < SEQ; k0 += 32) {
    // 8192 B per matrix = 8 chunks x 1024 B; wave w -> chunks {2w,2w+1} of each
#pragma unroll
    for (int it = 0; it < 2; it++) {
      int c = wave * 2 + it;                // chunk: rows [16c,16c+16)
      int row = c * 16 + lrow;
      async_cp16(&A[(size_t)(t0 + row) * SEQ + k0 + lcol], &Al[c * 512 + lane * 8]);
      async_cp16(&B[(size_t)(n0 + row) * SEQ + k0 + lcol], &Bl[c * 512 + lane * 8]);
    }
    __syncthreads();
    bf16x8 af[4], bfr[4];
#pragma unroll
    for (int i = 0; i < 4; i++) {
      af[i]  = *(const bf16x8*)&Al[(wm + i * 16 + lm) * 32 + q * 8];
      bfr[i] = *(const bf16x8*)&Bl[(wn + i * 16 + lm) * 32 + q * 8];
    }
#pragma unroll
    for (int mi = 0; mi < 4; mi++)
#pragma unroll
      for (int ni = 0; ni < 4; ni++)
        acc[mi][ni] = __builtin_amdgcn_mfma_f32_16x16x32_bf16(af[mi], bfr[ni], acc[mi][ni], 0, 0, 0);
    __syncthreads();
  }
  // nn = n0 + wn + ni*16 + lm;  n0+wn multiple of 64 -> b=(n0+wn)>>6 const, d=ni*16+lm
  const int bb = (n0 + wn) >> 6;
  float bias[4];
#pragma unroll
  for (int ni = 0; ni < 4; ni++) bias[ni] = bias_l[head * DH + ni * 16 + lm];
#pragma unroll
  for (int mi = 0; mi < 4; mi++)
#pragma unroll
    for (int ni = 0; ni < 4; ni++)
#pragma unroll
      for (int r = 0; r < 4; r++) {
        int t = t0 + wm + mi * 16 + q * 4 + r;
        int d = ni * 16 + lm;
        float vv = fmaxf(acc[mi][ni][r] + bias[ni], 0.f);
        hout[((size_t)bb * SEQ + t) * HID + head * DH + d] = (__bf16)vv;
      }
}

// ---------------- final dense: out[tok][dout] = sum_k h[tok][k]*lwb[dout][k] + lb (fp32 out) ----------------
__global__ __launch_bounds__(256) void dense_nat_k(
    const __bf16* __restrict__ hin, const __bf16* __restrict__ lwb,
    const float* __restrict__ lb, float* __restrict__ out) {
  __shared__ __bf16 Al[128 * 32];
  __shared__ __bf16 Bl[128 * 32];
  const int m0 = blockIdx.x * 128;
  const int n0 = blockIdx.y * 128;
  const int tid = threadIdx.x;
  const int wave = tid >> 6, lane = tid & 63;
  const int wm = (wave >> 1) << 6, wn = (wave & 1) << 6;
  const int lm = lane & 15, q = lane >> 4;
  const int lrow = lane >> 2, lcol = (lane & 3) * 8;
  f32x4 acc[4][4];
#pragma unroll
  for (int i = 0; i < 4; i++)
#pragma unroll
    for (int j = 0; j < 4; j++) acc[i][j] = {0.f, 0.f, 0.f, 0.f};

  for (int k0 = 0; k0 < HID; k0 += 32) {
#pragma unroll
    for (int it = 0; it < 2; it++) {
      int c = wave * 2 + it;
      int row = c * 16 + lrow;
      async_cp16(&hin[(size_t)(m0 + row) * HID + k0 + lcol], &Al[c * 512 + lane * 8]);
      async_cp16(&lwb[(size_t)(n0 + row) * HID + k0 + lcol], &Bl[c * 512 + lane * 8]);
    }
    __syncthreads();
    bf16x8 af[4], bfr[4];
#pragma unroll
    for (int i = 0; i < 4; i++) {
      af[i]  = *(const bf16x8*)&Al[(wm + i * 16 + lm) * 32 + q * 8];
      bfr[i] = *(const bf16x8*)&Bl[(wn + i * 16 + lm) * 32 + q * 8];
    }
#pragma unroll
    for (int mi = 0; mi < 4; mi++)
#pragma unroll
      for (int ni = 0; ni < 4; ni++)
        acc[mi][ni] = __builtin_amdgcn_mfma_f32_16x16x32_bf16(af[mi], bfr[ni], acc[mi][ni], 0, 0, 0);
    __syncthreads();
  }
#pragma unroll
  for (int mi = 0; mi < 4; mi++)
#pragma unroll
    for (int ni = 0; ni < 4; ni++) {
      float bias = lb[n0 + wn + ni * 16 + lm];
#pragma unroll
      for (int r = 0; r < 4; r++) {
        int tok = m0 + wm + mi * 16 + q * 4 + r;
        int n = n0 + wn + ni * 16 + lm;
        out[(size_t)tok * HID + n] = acc[mi][ni][r] + bias;
      }
    }
}

extern "C" void kernel_launch(void* const* d_in, const int* in_sizes, int n_in,
                              void* d_out, int out_size, void* d_ws, size_t ws_size,
                              hipStream_t stream) {
  const int*   x   = (const int*)d_in[0];
  const float* we  = (const float*)d_in[1];
  const float* pe  = (const float*)d_in[2];
  const float* te  = (const float*)d_in[3];
  const float* lng = (const float*)d_in[4];
  const float* lnb = (const float*)d_in[5];
  const float* W   = (const float*)d_in[6];   // [12][768][768] fp32
  const float* bb  = (const float*)d_in[7];   // [12][768] fp32
  const float* M   = (const float*)d_in[8];   // [12][12][512][512] fp32
  const float* lw  = (const float*)d_in[9];
  const float* lb  = (const float*)d_in[10];

  // workspace (bf16), ~141 MB total:
  __bf16* Mt  = (__bf16*)d_ws;                            // 12*12*512*512 = 75.5 MB
  __bf16* Wb  = Mt + (size_t)LAYERS * HEADS * SEQ * SEQ;  // 12*768*768    = 14.2 MB
  __bf16* lwb = Wb + (size_t)LAYERS * HID * HID;          // 768*768       = 1.2 MB
  __bf16* hA  = lwb + (size_t)HID * HID;                  // 16384*768     = 25.2 MB
  __bf16* X   = hA + (size_t)TOK * HID;                   // 12*2048*512   = 25.2 MB (per-head [2048][512])
  float* out = (float*)d_out;

  convert_k<<<LAYERS * HID * HID / 1024, 256, 0, stream>>>(W, Wb);
  convert_k<<<HID * HID / 1024, 256, 0, stream>>>(lw, lwb);
  transpose_all_m_k<<<dim3(8, 8, LAYERS * HEADS), 256, 0, stream>>>(M, Mt);
  embed_ln_k<<<TOK, 256, 0, stream>>>(x, we, pe, te, lng, lnb, hA);
  for (int l = 0; l < LAYERS; l++) {
    dense_t_k<<<dim3(TOK / 128, HID / 128), 256, 0, stream>>>(Wb + (size_t)l * HID * HID, hA, X);
    mix_relu_k<<<dim3(SEQ / 128, NPH / 128, HEADS), 256, 0, stream>>>(
        Mt + (size_t)l * HEADS * SEQ * SEQ, X, bb + (size_t)l * HID, hA);
  }
  dense_nat_k<<<dim3(TOK / 128, HID / 128), 256, 0, stream>>>(hA, lwb, lb, out);
}